// Round 1
// baseline (338.602 us; speedup 1.0000x reference)
//
#include <hip/hip_runtime.h>
#include <math.h>

// Problem constants (reference: B=64, TK=512, NK=256, H=512, fp32 in/out)
constexpr int kB = 64;
constexpr int kTK = 512;
constexpr int kNK = 256;
constexpr int kH = 512;

typedef float f32x4 __attribute__((ext_vector_type(4)));
typedef __bf16 bf16x8 __attribute__((ext_vector_type(8)));

__device__ __forceinline__ unsigned short f32_to_bf16(float f) {
  unsigned int u = __float_as_uint(f);
  u += 0x7fffu + ((u >> 16) & 1u);  // round-nearest-even
  return (unsigned short)(u >> 16);
}

// ---------------------------------------------------------------- pre-convert
__global__ void convert_w_kernel(const float* __restrict__ Wtok,
                                 const float* __restrict__ Wnode,
                                 unsigned short* __restrict__ WtokB,
                                 unsigned short* __restrict__ WnodeB) {
  const int i = blockIdx.x * blockDim.x + threadIdx.x;  // 262144 threads
  WtokB[i] = f32_to_bf16(Wtok[i]);
  WnodeB[i] = f32_to_bf16(Wnode[i]);
}

// ---------------------------------------------------------------- dec_fea
__global__ __launch_bounds__(512) void dec_fea_kernel(
    const float* __restrict__ s_t_hat, const float* __restrict__ W_dec,
    const float* __restrict__ b_dec, float* __restrict__ dec_fea) {
  __shared__ float sh[2 * kH];
  const int b = blockIdx.x, h = threadIdx.x;
  sh[h] = s_t_hat[(size_t)b * (2 * kH) + h];
  sh[h + kH] = s_t_hat[(size_t)b * (2 * kH) + kH + h];
  __syncthreads();
  float acc = 0.f;
#pragma unroll 16
  for (int k = 0; k < 2 * kH; ++k)
    acc = fmaf(sh[k], W_dec[(size_t)k * kH + h], acc);
  dec_fea[b * kH + h] = acc + b_dec[h];
}

// ---------------------------------------------------------------- fused scores
// Block: 512 threads (8 waves). Tile: 64 rows x all 512 cols, BK=32.
// Wave w owns cols [64w, 64w+64): 4x4 MFMA tiles of 16x16x32_bf16.
// Epilogue: scores[r] = sum_h v[h] * tanh(feat[r][h] + dec_fea[h] (+ flow[r]*W_c[h]))
template <int ROWS, bool IS_NODE>
__global__ __launch_bounds__(512) void scores_kernel(
    const float* __restrict__ A,            // [kB, ROWS, kH] fp32
    const unsigned short* __restrict__ Wb,  // [kH, kH] bf16 bits
    const float* __restrict__ dec_fea,      // [kB, kH]
    const float* __restrict__ flow,         // [kB, kNK] (node only)
    const float* __restrict__ W_c,          // [kH]     (node only)
    const float* __restrict__ v,            // [kH]
    float* __restrict__ scores)             // [kB, ROWS]
{
  constexpr int TILES_PER_B = ROWS / 64;
  const int b = blockIdx.x / TILES_PER_B;
  const int row0 = (blockIdx.x % TILES_PER_B) * 64;
  const int tid = threadIdx.x;
  const int wave = tid >> 6;
  const int lane = tid & 63;
  const int quad = lane >> 4;
  const int l15 = lane & 15;

  constexpr int LDA = 40;  // bf16 elems per LDS row: 32 + 8 pad (bank spread)
  __shared__ __align__(16) unsigned short As[64 * LDA];   // As[row][k]
  __shared__ __align__(16) unsigned short Bs[512 * LDA];  // Bs[n][k] (transposed)
  __shared__ float red[8][64];

  const f32x4 fzero = {0.f, 0.f, 0.f, 0.f};
  f32x4 acc[4][4];
#pragma unroll
  for (int i = 0; i < 4; ++i)
#pragma unroll
    for (int j = 0; j < 4; ++j) acc[i][j] = fzero;

  const int ar = tid >> 3;        // A staging: row 0..63
  const int ak = (tid & 7) * 4;   // A staging: k offset 0,4,..,28
  const float* aptr = A + ((size_t)(b * ROWS + row0 + ar)) * kH + ak;
  const int n0 = wave * 64;

  for (int kc = 0; kc < kH; kc += 32) {
    // stage A tile (64x32) f32 -> bf16, k-contiguous
    float4 af = *(const float4*)(aptr + kc);
    ushort4 ah;
    ah.x = f32_to_bf16(af.x);
    ah.y = f32_to_bf16(af.y);
    ah.z = f32_to_bf16(af.z);
    ah.w = f32_to_bf16(af.w);
    *(ushort4*)&As[ar * LDA + ak] = ah;
    // stage B tile (32x512) transposed into Bs[n][k]; loads coalesced over n
    {
      const int n = tid;
#pragma unroll
      for (int k4 = 0; k4 < 8; ++k4) {
        ushort4 bh;
        bh.x = Wb[(size_t)(kc + k4 * 4 + 0) * kH + n];
        bh.y = Wb[(size_t)(kc + k4 * 4 + 1) * kH + n];
        bh.z = Wb[(size_t)(kc + k4 * 4 + 2) * kH + n];
        bh.w = Wb[(size_t)(kc + k4 * 4 + 3) * kH + n];
        *(ushort4*)&Bs[n * LDA + k4 * 4] = bh;
      }
    }
    __syncthreads();
    // MFMA: A-frag A[m=l15][k=quad*8+j], B-frag B[k=quad*8+j][n=l15]
    bf16x8 afr[4], bfr[4];
#pragma unroll
    for (int mi = 0; mi < 4; ++mi)
      afr[mi] = *(const bf16x8*)&As[(16 * mi + l15) * LDA + quad * 8];
#pragma unroll
    for (int ni = 0; ni < 4; ++ni)
      bfr[ni] = *(const bf16x8*)&Bs[(n0 + 16 * ni + l15) * LDA + quad * 8];
#pragma unroll
    for (int mi = 0; mi < 4; ++mi)
#pragma unroll
      for (int ni = 0; ni < 4; ++ni)
        acc[mi][ni] = __builtin_amdgcn_mfma_f32_16x16x32_bf16(
            afr[mi], bfr[ni], acc[mi][ni], 0, 0, 0);
    __syncthreads();
  }

  // fused epilogue; C/D layout: col = l15 (+16*ni+n0), row = quad*4 + reg (+16*mi)
  float dec4[4], vv4[4], wc4[4];
#pragma unroll
  for (int ni = 0; ni < 4; ++ni) {
    const int col = n0 + 16 * ni + l15;
    dec4[ni] = dec_fea[b * kH + col];
    vv4[ni] = v[col];
    if constexpr (IS_NODE) wc4[ni] = W_c[col]; else wc4[ni] = 0.f;
  }
#pragma unroll
  for (int mi = 0; mi < 4; ++mi) {
#pragma unroll
    for (int reg = 0; reg < 4; ++reg) {
      const int row = 16 * mi + quad * 4 + reg;
      float fl = 0.f;
      if constexpr (IS_NODE) fl = flow[b * kNK + row0 + row];
      float p = 0.f;
#pragma unroll
      for (int ni = 0; ni < 4; ++ni) {
        float val = acc[mi][ni][reg] + dec4[ni];
        if constexpr (IS_NODE) val = fmaf(fl, wc4[ni], val);
        p += tanhf(val) * vv4[ni];
      }
      // reduce across the 16 lanes sharing this row (butterfly within 16-group)
#pragma unroll
      for (int off = 1; off < 16; off <<= 1) p += __shfl_xor(p, off, 64);
      if (l15 == 0) red[wave][row] = p;
    }
  }
  __syncthreads();
  if (tid < 64) {
    float s = 0.f;
#pragma unroll
    for (int w = 0; w < 8; ++w) s += red[w][tid];
    scores[b * ROWS + row0 + tid] = s;
  }
}

// ---------------------------------------------------------------- softmax/mix
__device__ __forceinline__ float block_max_512(float v, float* rbuf) {
#pragma unroll
  for (int off = 32; off >= 1; off >>= 1) v = fmaxf(v, __shfl_xor(v, off, 64));
  if ((threadIdx.x & 63) == 0) rbuf[threadIdx.x >> 6] = v;
  __syncthreads();
  float m = rbuf[0];
#pragma unroll
  for (int w = 1; w < 8; ++w) m = fmaxf(m, rbuf[w]);
  __syncthreads();
  return m;
}

__device__ __forceinline__ float block_sum_512(float v, float* rbuf) {
#pragma unroll
  for (int off = 32; off >= 1; off >>= 1) v += __shfl_xor(v, off, 64);
  if ((threadIdx.x & 63) == 0) rbuf[threadIdx.x >> 6] = v;
  __syncthreads();
  float s = rbuf[0];
#pragma unroll
  for (int w = 1; w < 8; ++w) s += rbuf[w];
  __syncthreads();
  return s;
}

__global__ __launch_bounds__(512) void softmax_mix_kernel(
    const float* __restrict__ scores_node, const float* __restrict__ scores_tok,
    const int* __restrict__ node_to_token,
    const float* __restrict__ mask_tok, const float* __restrict__ mask_node,
    float* __restrict__ out_final, float* __restrict__ out_attn_node) {
  const int b = blockIdx.x, tid = threadIdx.x;
  __shared__ float an_sh[kNK];
  __shared__ float rbuf[8];

  // node: softmax -> *mask -> renorm
  float sn = (tid < kNK) ? scores_node[b * kNK + tid] : -INFINITY;
  float m = block_max_512(sn, rbuf);
  float e = (tid < kNK) ? expf(sn - m) : 0.f;
  float s = block_sum_512(e, rbuf);
  float pm = (tid < kNK) ? (e / s) * mask_node[b * kNK + tid] : 0.f;
  float s2 = block_sum_512(pm, rbuf);
  float an = pm / s2;
  if (tid < kNK) {
    an_sh[tid] = an;
    out_attn_node[b * kNK + tid] = an;
  }
  __syncthreads();

  // gather node attn onto tokens, then softmax -> *mask -> renorm
  const float mt = mask_tok[b * kTK + tid];
  const int idx = node_to_token[b * kTK + tid];
  float g = an_sh[idx];
  float m2 = block_max_512(g, rbuf);
  float e2 = expf(g - m2);
  float sg = block_sum_512(e2, rbuf);
  float pg = (e2 / sg) * mt;
  float sg2 = block_sum_512(pg, rbuf);
  float an2t = pg / sg2;

  // token: softmax -> *mask -> renorm
  float st = scores_tok[b * kTK + tid];
  float m3 = block_max_512(st, rbuf);
  float e3 = expf(st - m3);
  float s3 = block_sum_512(e3, rbuf);
  float pt = (e3 / s3) * mt;
  float s32 = block_sum_512(pt, rbuf);
  float at = pt / s32;

  out_final[b * kTK + tid] = 0.5f * (at + an2t);
}

// ---------------------------------------------------------------- c_t
__global__ __launch_bounds__(512) void ct_kernel(const float* __restrict__ final_attn,
                                                 const float* __restrict__ enc_tok,
                                                 float* __restrict__ out_ct) {
  const int b = blockIdx.x, h = threadIdx.x;
  __shared__ float fa[kTK];
  fa[h] = final_attn[b * kTK + h];
  __syncthreads();
  float acc = 0.f;
#pragma unroll 8
  for (int t = 0; t < kTK; ++t)
    acc = fmaf(fa[t], enc_tok[((size_t)(b * kTK + t)) * kH + h], acc);
  out_ct[b * kH + h] = acc;
}

// ---------------------------------------------------------------- graph 2-hop
__global__ __launch_bounds__(256) void flow_kernel(const float* __restrict__ attn_node,
                                                   const float* __restrict__ graph,
                                                   float* __restrict__ out_flow) {
  const int b = blockIdx.x, mcol = threadIdx.x;
  __shared__ float z[kNK];
  __shared__ float oneh[kNK];
  z[mcol] = attn_node[b * kNK + mcol];
  __syncthreads();
  float acc = 0.f;
#pragma unroll 8
  for (int n = 0; n < kNK; ++n)
    acc = fmaf(z[n], graph[((size_t)(b * kNK + n)) * kNK + mcol], acc);
  oneh[mcol] = acc;
  __syncthreads();
  float acc2 = 0.f;
#pragma unroll 8
  for (int n = 0; n < kNK; ++n)
    acc2 = fmaf(oneh[n], graph[((size_t)(b * kNK + n)) * kNK + mcol], acc2);
  out_flow[b * kNK + mcol] = (z[mcol] + acc + acc2) * 0.33333f;
}

// ---------------------------------------------------------------- launch
extern "C" void kernel_launch(void* const* d_in, const int* in_sizes, int n_in,
                              void* d_out, int out_size, void* d_ws, size_t ws_size,
                              hipStream_t stream) {
  (void)in_sizes; (void)n_in; (void)out_size; (void)ws_size;
  const float* s_t_hat  = (const float*)d_in[0];
  const float* enc_tok  = (const float*)d_in[1];
  const float* enc_node = (const float*)d_in[2];
  const int*   n2t      = (const int*)d_in[3];
  const float* mask_tok = (const float*)d_in[4];
  const float* mask_nd  = (const float*)d_in[5];
  const float* graph    = (const float*)d_in[6];
  const float* flow     = (const float*)d_in[7];
  const float* W_c      = (const float*)d_in[8];
  const float* W_tok    = (const float*)d_in[9];
  const float* W_node   = (const float*)d_in[10];
  const float* W_dec    = (const float*)d_in[11];
  const float* b_dec    = (const float*)d_in[12];
  const float* v_tok    = (const float*)d_in[13];
  const float* v_node   = (const float*)d_in[14];

  float* out = (float*)d_out;   // c_t | final_attn | attn_dist_node | flow_out
  float* out_ct        = out;
  float* out_final     = out + kB * kH;
  float* out_attn_node = out + 2 * kB * kH;
  float* out_flow      = out_attn_node + kB * kNK;

  // workspace: dec_fea (32768 f) | scores_tok (32768 f) | scores_node (16384 f)
  //            | W_tok bf16 (512KB) | W_node bf16 (512KB)  -> ~1.35 MB total
  float* ws = (float*)d_ws;
  float* dec_fea_buf = ws;
  float* scores_tok  = ws + kB * kH;
  float* scores_node = ws + 2 * kB * kH;
  unsigned short* WtokB  = (unsigned short*)(ws + 2 * kB * kH + kB * kNK);
  unsigned short* WnodeB = WtokB + kH * kH;

  convert_w_kernel<<<(kH * kH) / 256, 256, 0, stream>>>(W_tok, W_node, WtokB, WnodeB);
  dec_fea_kernel<<<kB, 512, 0, stream>>>(s_t_hat, W_dec, b_dec, dec_fea_buf);
  scores_kernel<kTK, false><<<kB * kTK / 64, 512, 0, stream>>>(
      enc_tok, WtokB, dec_fea_buf, nullptr, nullptr, v_tok, scores_tok);
  scores_kernel<kNK, true><<<kB * kNK / 64, 512, 0, stream>>>(
      enc_node, WnodeB, dec_fea_buf, flow, W_c, v_node, scores_node);
  softmax_mix_kernel<<<kB, 512, 0, stream>>>(scores_node, scores_tok, n2t,
                                             mask_tok, mask_nd, out_final, out_attn_node);
  ct_kernel<<<kB, 512, 0, stream>>>(out_final, enc_tok, out_ct);
  flow_kernel<<<kB, 256, 0, stream>>>(out_attn_node, graph, out_flow);
}

// Round 2
// 272.961 us; speedup vs baseline: 1.2405x; 1.2405x over previous
//
#include <hip/hip_runtime.h>
#include <math.h>

// Problem constants (reference: B=64, TK=512, NK=256, H=512, fp32 in/out)
constexpr int kB = 64;
constexpr int kTK = 512;
constexpr int kNK = 256;
constexpr int kH = 512;

typedef float f32x4 __attribute__((ext_vector_type(4)));
typedef __bf16 bf16x8 __attribute__((ext_vector_type(8)));

__device__ __forceinline__ unsigned short f32_to_bf16(float f) {
  unsigned int u = __float_as_uint(f);
  u += 0x7fffu + ((u >> 16) & 1u);  // round-nearest-even
  return (unsigned short)(u >> 16);
}

__device__ __forceinline__ float tanh_fast(float x) {
  // tanh(x) = 1 - 2/(e^{2x}+1); e^{2x} = 2^{x*2.885390...}
  float e = __builtin_amdgcn_exp2f(x * 2.8853900817779268f);
  return 1.0f - 2.0f * __builtin_amdgcn_rcpf(e + 1.0f);
}

// -------------------------------------------------- W transpose+convert (bf16 [n][k])
// grid (16,16,2), block (32,8). z selects tok/node.
__global__ __launch_bounds__(256) void transpose_w_kernel(
    const float* __restrict__ Wtok, const float* __restrict__ Wnode,
    unsigned short* __restrict__ WtokT, unsigned short* __restrict__ WnodeT) {
  const float* W = blockIdx.z ? Wnode : Wtok;
  unsigned short* T = blockIdx.z ? WnodeT : WtokT;
  __shared__ float tile[32][33];
  const int tx = threadIdx.x, ty = threadIdx.y;
  const int bx = blockIdx.x, by = blockIdx.y;
#pragma unroll
  for (int i = 0; i < 4; ++i)
    tile[ty + 8 * i][tx] = W[(size_t)(by * 32 + ty + 8 * i) * kH + bx * 32 + tx];
  __syncthreads();
#pragma unroll
  for (int i = 0; i < 4; ++i)
    T[(size_t)(bx * 32 + ty + 8 * i) * kH + by * 32 + tx] =
        f32_to_bf16(tile[tx][ty + 8 * i]);
}

// ---------------------------------------------------------------- dec_fea
__global__ __launch_bounds__(512) void dec_fea_kernel(
    const float* __restrict__ s_t_hat, const float* __restrict__ W_dec,
    const float* __restrict__ b_dec, float* __restrict__ dec_fea) {
  __shared__ float sh[2 * kH];
  const int b = blockIdx.x, h = threadIdx.x;
  sh[h] = s_t_hat[(size_t)b * (2 * kH) + h];
  sh[h + kH] = s_t_hat[(size_t)b * (2 * kH) + kH + h];
  __syncthreads();
  float acc = 0.f;
#pragma unroll 16
  for (int k = 0; k < 2 * kH; ++k)
    acc = fmaf(sh[k], W_dec[(size_t)k * kH + h], acc);
  dec_fea[b * kH + h] = acc + b_dec[h];
}

// ---------------------------------------------------------------- fused scores
// 1024 threads (16 waves). Block tile: 64 rows x 512 cols, BK=64, 8 chunks.
// Wave w owns cols [32w, 32w+32): 4(m) x 2(n) MFMA tiles of 16x16x32_bf16.
// B-frags straight from global (WT bf16 [n][k], L2-resident) -- no LDS, no barrier.
// A double-buffered in LDS: ONE barrier per chunk.
template <int ROWS, bool IS_NODE>
__global__ __launch_bounds__(1024, 4) void scores_kernel(
    const float* __restrict__ A,            // [kB, ROWS, kH] fp32
    const unsigned short* __restrict__ WT,  // [kH(n), kH(k)] bf16 bits (transposed)
    const float* __restrict__ dec_fea,      // [kB, kH]
    const float* __restrict__ flow,         // [kB, kNK] (node only)
    const float* __restrict__ W_c,          // [kH]     (node only)
    const float* __restrict__ v,            // [kH]
    float* __restrict__ scores)             // [kB, ROWS]
{
  constexpr int TILES_PER_B = ROWS / 64;
  const int b = blockIdx.x / TILES_PER_B;
  const int row0 = (blockIdx.x % TILES_PER_B) * 64;
  const int tid = threadIdx.x;
  const int wave = tid >> 6;        // 0..15
  const int lane = tid & 63;
  const int quad = lane >> 4;
  const int l15 = lane & 15;
  const int n0 = wave * 32;

  constexpr int LDA = 72;  // ushorts per LDS row: 64 + 8 pad (144B, 16B-aligned)
  __shared__ __align__(16) unsigned short As[2 * 64 * LDA];
  __shared__ float red[16][64];

  const f32x4 fzero = {0.f, 0.f, 0.f, 0.f};
  f32x4 acc[4][2];
#pragma unroll
  for (int i = 0; i < 4; ++i)
#pragma unroll
    for (int j = 0; j < 2; ++j) acc[i][j] = fzero;

  // A staging map: thread -> (row r, k-offset k0), one float4 per chunk
  const int r = tid >> 4;          // 0..63
  const int k0 = (tid & 15) * 4;   // 0..60
  const float* aptr = A + ((size_t)(b * ROWS + row0 + r)) * kH + k0;

  // prologue: stage chunk 0 into buffer 0
  {
    float4 af = *(const float4*)(aptr);
    ushort4 ah;
    ah.x = f32_to_bf16(af.x); ah.y = f32_to_bf16(af.y);
    ah.z = f32_to_bf16(af.z); ah.w = f32_to_bf16(af.w);
    *(ushort4*)&As[r * LDA + k0] = ah;
  }

  const unsigned short* wt_base = WT + (size_t)(n0 + l15) * kH + quad * 8;

#pragma unroll 1
  for (int kc8 = 0; kc8 < 8; ++kc8) {
    __syncthreads();
    const unsigned short* Ac = As + (kc8 & 1) * (64 * LDA);

    // B fragments from global (L2): 16B per lane, 64B-line-coalesced
    bf16x8 bfr[2][2];
#pragma unroll
    for (int kh = 0; kh < 2; ++kh)
#pragma unroll
      for (int ni = 0; ni < 2; ++ni)
        bfr[kh][ni] = *(const bf16x8*)(wt_base + (size_t)(16 * ni) * kH +
                                       kc8 * 64 + kh * 32);

    // A fragments from LDS
    bf16x8 afr[2][4];
#pragma unroll
    for (int kh = 0; kh < 2; ++kh)
#pragma unroll
      for (int mi = 0; mi < 4; ++mi)
        afr[kh][mi] =
            *(const bf16x8*)&Ac[(16 * mi + l15) * LDA + kh * 32 + quad * 8];

    // stage next chunk into the other buffer (safe: its readers passed the
    // barrier above at iteration kc8-1)
    if (kc8 < 7) {
      float4 af = *(const float4*)(aptr + (kc8 + 1) * 64);
      ushort4 ah;
      ah.x = f32_to_bf16(af.x); ah.y = f32_to_bf16(af.y);
      ah.z = f32_to_bf16(af.z); ah.w = f32_to_bf16(af.w);
      *(ushort4*)&As[((kc8 + 1) & 1) * (64 * LDA) + r * LDA + k0] = ah;
    }

#pragma unroll
    for (int kh = 0; kh < 2; ++kh)
#pragma unroll
      for (int mi = 0; mi < 4; ++mi)
#pragma unroll
        for (int ni = 0; ni < 2; ++ni)
          acc[mi][ni] = __builtin_amdgcn_mfma_f32_16x16x32_bf16(
              afr[kh][mi], bfr[kh][ni], acc[mi][ni], 0, 0, 0);
  }

  // fused epilogue; C/D layout: col = n0+16ni+l15, row = 16mi+quad*4+reg
  float dec2[2], vv2[2], wc2[2];
#pragma unroll
  for (int ni = 0; ni < 2; ++ni) {
    const int col = n0 + 16 * ni + l15;
    dec2[ni] = dec_fea[b * kH + col];
    vv2[ni] = v[col];
    if constexpr (IS_NODE) wc2[ni] = W_c[col]; else wc2[ni] = 0.f;
  }
#pragma unroll
  for (int mi = 0; mi < 4; ++mi) {
#pragma unroll
    for (int reg = 0; reg < 4; ++reg) {
      const int row = 16 * mi + quad * 4 + reg;
      float fl = 0.f;
      if constexpr (IS_NODE) fl = flow[b * kNK + row0 + row];
      float p = 0.f;
#pragma unroll
      for (int ni = 0; ni < 2; ++ni) {
        float val = acc[mi][ni][reg] + dec2[ni];
        if constexpr (IS_NODE) val = fmaf(fl, wc2[ni], val);
        p += tanh_fast(val) * vv2[ni];
      }
#pragma unroll
      for (int off = 1; off < 16; off <<= 1) p += __shfl_xor(p, off, 64);
      if (l15 == 0) red[wave][row] = p;
    }
  }
  __syncthreads();
  if (tid < 64) {
    float s = 0.f;
#pragma unroll
    for (int w = 0; w < 16; ++w) s += red[w][tid];
    scores[b * ROWS + row0 + tid] = s;
  }
}

// ---------------------------------------------------------------- softmax/mix
__device__ __forceinline__ float block_max_512(float v, float* rbuf) {
#pragma unroll
  for (int off = 32; off >= 1; off >>= 1) v = fmaxf(v, __shfl_xor(v, off, 64));
  if ((threadIdx.x & 63) == 0) rbuf[threadIdx.x >> 6] = v;
  __syncthreads();
  float m = rbuf[0];
#pragma unroll
  for (int w = 1; w < 8; ++w) m = fmaxf(m, rbuf[w]);
  __syncthreads();
  return m;
}

__device__ __forceinline__ float block_sum_512(float v, float* rbuf) {
#pragma unroll
  for (int off = 32; off >= 1; off >>= 1) v += __shfl_xor(v, off, 64);
  if ((threadIdx.x & 63) == 0) rbuf[threadIdx.x >> 6] = v;
  __syncthreads();
  float s = rbuf[0];
#pragma unroll
  for (int w = 1; w < 8; ++w) s += rbuf[w];
  __syncthreads();
  return s;
}

__global__ __launch_bounds__(512) void softmax_mix_kernel(
    const float* __restrict__ scores_node, const float* __restrict__ scores_tok,
    const int* __restrict__ node_to_token,
    const float* __restrict__ mask_tok, const float* __restrict__ mask_node,
    float* __restrict__ out_final, float* __restrict__ out_attn_node) {
  const int b = blockIdx.x, tid = threadIdx.x;
  __shared__ float an_sh[kNK];
  __shared__ float rbuf[8];

  // node: softmax -> *mask -> renorm
  float sn = (tid < kNK) ? scores_node[b * kNK + tid] : -INFINITY;
  float m = block_max_512(sn, rbuf);
  float e = (tid < kNK) ? expf(sn - m) : 0.f;
  float s = block_sum_512(e, rbuf);
  float pm = (tid < kNK) ? (e / s) * mask_node[b * kNK + tid] : 0.f;
  float s2 = block_sum_512(pm, rbuf);
  float an = pm / s2;
  if (tid < kNK) {
    an_sh[tid] = an;
    out_attn_node[b * kNK + tid] = an;
  }
  __syncthreads();

  // gather node attn onto tokens, then softmax -> *mask -> renorm
  const float mt = mask_tok[b * kTK + tid];
  const int idx = node_to_token[b * kTK + tid];
  float g = an_sh[idx];
  float m2 = block_max_512(g, rbuf);
  float e2 = expf(g - m2);
  float sg = block_sum_512(e2, rbuf);
  float pg = (e2 / sg) * mt;
  float sg2 = block_sum_512(pg, rbuf);
  float an2t = pg / sg2;

  // token: softmax -> *mask -> renorm
  float st = scores_tok[b * kTK + tid];
  float m3 = block_max_512(st, rbuf);
  float e3 = expf(st - m3);
  float s3 = block_sum_512(e3, rbuf);
  float pt = (e3 / s3) * mt;
  float s32 = block_sum_512(pt, rbuf);
  float at = pt / s32;

  out_final[b * kTK + tid] = 0.5f * (at + an2t);
}

// ---------------------------------------------------------------- c_t (partial + reduce)
// grid (4, 64): block (slice s, batch b); each handles 128 token rows.
__global__ __launch_bounds__(512) void ct_partial_kernel(
    const float* __restrict__ final_attn, const float* __restrict__ enc_tok,
    float* __restrict__ ctp) {
  const int s = blockIdx.x, b = blockIdx.y, h = threadIdx.x;
  __shared__ float fa[128];
  if (h < 128) fa[h] = final_attn[b * kTK + s * 128 + h];
  __syncthreads();
  float acc = 0.f;
  const float* base = enc_tok + ((size_t)(b * kTK + s * 128)) * kH + h;
#pragma unroll 8
  for (int t = 0; t < 128; ++t)
    acc = fmaf(fa[t], base[(size_t)t * kH], acc);
  ctp[(size_t)(b * 4 + s) * kH + h] = acc;
}

__global__ __launch_bounds__(512) void ct_reduce_kernel(
    const float* __restrict__ ctp, float* __restrict__ out_ct) {
  const int b = blockIdx.x, h = threadIdx.x;
  float acc = 0.f;
#pragma unroll
  for (int s = 0; s < 4; ++s) acc += ctp[(size_t)(b * 4 + s) * kH + h];
  out_ct[b * kH + h] = acc;
}

// ---------------------------------------------------------------- graph 2-hop
// flow1: partial one_hop over n-slices. grid (8, 64), 256 threads.
__global__ __launch_bounds__(256) void flow1_kernel(
    const float* __restrict__ attn_node, const float* __restrict__ graph,
    float* __restrict__ fp1) {
  const int s = blockIdx.x, b = blockIdx.y, m = threadIdx.x;
  __shared__ float z[32];
  if (m < 32) z[m] = attn_node[b * kNK + s * 32 + m];
  __syncthreads();
  float acc = 0.f;
  const float* g = graph + ((size_t)(b * kNK + s * 32)) * kNK + m;
#pragma unroll 8
  for (int n = 0; n < 32; ++n) acc = fmaf(z[n], g[(size_t)n * kNK], acc);
  fp1[(b * 8 + s) * kNK + m] = acc;
}

// flow3: partial two_hop (reconstructs one_hop slice from fp1). grid (8, 64).
__global__ __launch_bounds__(256) void flow3_kernel(
    const float* __restrict__ fp1, const float* __restrict__ graph,
    float* __restrict__ fp2) {
  const int s = blockIdx.x, b = blockIdx.y, m = threadIdx.x;
  __shared__ float one[32];
  if (m < 32) {
    float o = 0.f;
#pragma unroll
    for (int sp = 0; sp < 8; ++sp) o += fp1[(b * 8 + sp) * kNK + s * 32 + m];
    one[m] = o;
  }
  __syncthreads();
  float acc = 0.f;
  const float* g = graph + ((size_t)(b * kNK + s * 32)) * kNK + m;
#pragma unroll 8
  for (int n = 0; n < 32; ++n) acc = fmaf(one[n], g[(size_t)n * kNK], acc);
  fp2[(b * 8 + s) * kNK + m] = acc;
}

// flow4: combine. grid 64, 256 threads.
__global__ __launch_bounds__(256) void flow4_kernel(
    const float* __restrict__ fp1, const float* __restrict__ fp2,
    const float* __restrict__ attn_node, float* __restrict__ out_flow) {
  const int b = blockIdx.x, m = threadIdx.x;
  float one = 0.f, two = 0.f;
#pragma unroll
  for (int s = 0; s < 8; ++s) {
    one += fp1[(b * 8 + s) * kNK + m];
    two += fp2[(b * 8 + s) * kNK + m];
  }
  out_flow[b * kNK + m] = (attn_node[b * kNK + m] + one + two) * 0.33333f;
}

// ---------------------------------------------------------------- launch
extern "C" void kernel_launch(void* const* d_in, const int* in_sizes, int n_in,
                              void* d_out, int out_size, void* d_ws, size_t ws_size,
                              hipStream_t stream) {
  (void)in_sizes; (void)n_in; (void)out_size; (void)ws_size;
  const float* s_t_hat  = (const float*)d_in[0];
  const float* enc_tok  = (const float*)d_in[1];
  const float* enc_node = (const float*)d_in[2];
  const int*   n2t      = (const int*)d_in[3];
  const float* mask_tok = (const float*)d_in[4];
  const float* mask_nd  = (const float*)d_in[5];
  const float* graph    = (const float*)d_in[6];
  const float* flow     = (const float*)d_in[7];
  const float* W_c      = (const float*)d_in[8];
  const float* W_tok    = (const float*)d_in[9];
  const float* W_node   = (const float*)d_in[10];
  const float* W_dec    = (const float*)d_in[11];
  const float* b_dec    = (const float*)d_in[12];
  const float* v_tok    = (const float*)d_in[13];
  const float* v_node   = (const float*)d_in[14];

  float* out = (float*)d_out;   // c_t | final_attn | attn_dist_node | flow_out
  float* out_ct        = out;
  float* out_final     = out + kB * kH;
  float* out_attn_node = out + 2 * kB * kH;
  float* out_flow      = out_attn_node + kB * kNK;

  // workspace layout (floats):
  // dec_fea 32768 | scores_tok 32768 | scores_node 16384 | fp1 131072/8? ...
  float* ws = (float*)d_ws;
  float* dec_fea_buf = ws;                               // 32768
  float* scores_tok  = ws + 32768;                       // 32768
  float* scores_node = ws + 65536;                       // 16384
  float* fp1         = ws + 81920;                       // 64*8*256 = 131072
  float* fp2         = ws + 81920 + 131072;              // 131072
  unsigned short* WtokT  = (unsigned short*)(ws + 344064);  // 512KB (65536 f)
  unsigned short* WnodeT = WtokT + kH * kH;                 // 512KB (65536 f)
  // ct partials alias the W buffers (scores kernels are done before ct runs)
  float* ctp = (float*)WtokT;                            // 64*4*512 = 131072 f

  transpose_w_kernel<<<dim3(16, 16, 2), dim3(32, 8), 0, stream>>>(
      W_tok, W_node, WtokT, WnodeT);
  dec_fea_kernel<<<kB, 512, 0, stream>>>(s_t_hat, W_dec, b_dec, dec_fea_buf);
  scores_kernel<kTK, false><<<kB * kTK / 64, 1024, 0, stream>>>(
      enc_tok, WtokT, dec_fea_buf, nullptr, nullptr, v_tok, scores_tok);
  scores_kernel<kNK, true><<<kB * kNK / 64, 1024, 0, stream>>>(
      enc_node, WnodeT, dec_fea_buf, flow, W_c, v_node, scores_node);
  softmax_mix_kernel<<<kB, 512, 0, stream>>>(scores_node, scores_tok, n2t,
                                             mask_tok, mask_nd, out_final, out_attn_node);
  ct_partial_kernel<<<dim3(4, kB), 512, 0, stream>>>(out_final, enc_tok, ctp);
  ct_reduce_kernel<<<kB, 512, 0, stream>>>(ctp, out_ct);
  flow1_kernel<<<dim3(8, kB), 256, 0, stream>>>(out_attn_node, graph, fp1);
  flow3_kernel<<<dim3(8, kB), 256, 0, stream>>>(fp1, graph, fp2);
  flow4_kernel<<<kB, 256, 0, stream>>>(fp1, fp2, out_attn_node, out_flow);
}

// Round 3
// 248.052 us; speedup vs baseline: 1.3650x; 1.1004x over previous
//
#include <hip/hip_runtime.h>
#include <math.h>

// Problem constants (reference: B=64, TK=512, NK=256, H=512, fp32 in/out)
constexpr int kB = 64;
constexpr int kTK = 512;
constexpr int kNK = 256;
constexpr int kH = 512;

typedef float f32x4 __attribute__((ext_vector_type(4)));
typedef __bf16 bf16x8 __attribute__((ext_vector_type(8)));
typedef unsigned short u16x8 __attribute__((ext_vector_type(8)));

__device__ __forceinline__ unsigned short f32_to_bf16(float f) {
  unsigned int u = __float_as_uint(f);
  u += 0x7fffu + ((u >> 16) & 1u);  // round-nearest-even
  return (unsigned short)(u >> 16);
}

__device__ __forceinline__ float tanh_fast(float x) {
  // tanh(x) = 1 - 2/(e^{2x}+1); e^{2x} = 2^{x*2.885390...}
  float e = __builtin_amdgcn_exp2f(x * 2.8853900817779268f);
  return 1.0f - 2.0f * __builtin_amdgcn_rcpf(e + 1.0f);
}

// -------------------------------------------------- W transpose+convert (bf16 [n][k])
__global__ __launch_bounds__(256) void transpose_w_kernel(
    const float* __restrict__ Wtok, const float* __restrict__ Wnode,
    unsigned short* __restrict__ WtokT, unsigned short* __restrict__ WnodeT) {
  const float* W = blockIdx.z ? Wnode : Wtok;
  unsigned short* T = blockIdx.z ? WnodeT : WtokT;
  __shared__ float tile[32][33];
  const int tx = threadIdx.x, ty = threadIdx.y;
  const int bx = blockIdx.x, by = blockIdx.y;
#pragma unroll
  for (int i = 0; i < 4; ++i)
    tile[ty + 8 * i][tx] = W[(size_t)(by * 32 + ty + 8 * i) * kH + bx * 32 + tx];
  __syncthreads();
#pragma unroll
  for (int i = 0; i < 4; ++i)
    T[(size_t)(bx * 32 + ty + 8 * i) * kH + by * 32 + tx] =
        f32_to_bf16(tile[tx][ty + 8 * i]);
}

// ---------------------------------------------------------------- dec_fea (split-K)
__global__ __launch_bounds__(512) void dec_partial_kernel(
    const float* __restrict__ s_t_hat, const float* __restrict__ W_dec,
    float* __restrict__ part) {
  const int b = blockIdx.x, s = blockIdx.y, h = threadIdx.x;
  __shared__ float sh[128];
  if (h < 128) sh[h] = s_t_hat[(size_t)b * (2 * kH) + s * 128 + h];
  __syncthreads();
  float acc = 0.f;
  const float* w = W_dec + (size_t)(s * 128) * kH + h;
#pragma unroll 8
  for (int k = 0; k < 128; ++k) acc = fmaf(sh[k], w[(size_t)k * kH], acc);
  part[(size_t)(b * 8 + s) * kH + h] = acc;
}

__global__ __launch_bounds__(512) void dec_reduce_kernel(
    const float* __restrict__ part, const float* __restrict__ b_dec,
    float* __restrict__ dec_fea) {
  const int b = blockIdx.x, h = threadIdx.x;
  float acc = b_dec[h];
#pragma unroll
  for (int s = 0; s < 8; ++s) acc += part[(size_t)(b * 8 + s) * kH + h];
  dec_fea[b * kH + h] = acc;
}

// ---------------------------------------------------------------- fused scores
// 512 threads (8 waves). Block tile: 64 rows x 512 cols, BK=64, 8 chunks.
// Wave w owns cols [64w, 64w+64): 4(m) x 4(n) MFMA tiles of 16x16x32_bf16.
// B-frags from global L2 (WT bf16 [n][k]), register-double-buffered one chunk
// ahead so the L2 latency is hidden behind the current chunk's compute.
// A tile staged fp32->bf16 into LDS in FRAGMENT-MAJOR layout: frag slot
// (kh*4+mi)*64 + lane, 16 B per lane -> ds_write_b128 / ds_read_b128,
// conflict-minimal, one barrier per chunk.
template <int ROWS, bool IS_NODE>
__global__ __launch_bounds__(512, 2) void scores_kernel(
    const float* __restrict__ A,            // [kB, ROWS, kH] fp32
    const unsigned short* __restrict__ WT,  // [kH(n), kH(k)] bf16 bits
    const float* __restrict__ dec_fea,      // [kB, kH]
    const float* __restrict__ flow,         // [kB, kNK] (node only)
    const float* __restrict__ W_c,          // [kH]     (node only)
    const float* __restrict__ v,            // [kH]
    float* __restrict__ scores)             // [kB, ROWS]
{
  constexpr int TILES_PER_B = ROWS / 64;
  const int b = blockIdx.x / TILES_PER_B;
  const int row0 = (blockIdx.x % TILES_PER_B) * 64;
  const int tid = threadIdx.x;
  const int wave = tid >> 6;  // 0..7
  const int lane = tid & 63;
  const int quad = lane >> 4;
  const int l15 = lane & 15;
  const int n0 = wave * 64;

  __shared__ __align__(16) unsigned short As[2][4096];  // 8 KB per buffer
  __shared__ float red[8][64];

  const f32x4 fzero = {0.f, 0.f, 0.f, 0.f};
  f32x4 acc[4][4];
#pragma unroll
  for (int i = 0; i < 4; ++i)
#pragma unroll
    for (int j = 0; j < 4; ++j) acc[i][j] = fzero;

  // A staging map: thread -> (row sr, k-block kq); writes ONE 16B frag slot.
  const int sr = tid >> 3;  // 0..63
  const int kq = tid & 7;   // k0 = 8*kq
  const int slot = (((kq >> 2) * 4 + (sr >> 4)) * 64 + (kq & 3) * 16 + (sr & 15)) * 8;
  const float* aptr = A + ((size_t)(b * ROWS + row0 + sr)) * kH + kq * 8;

  auto stage = [&](int kc, int buf) {
    float4 a0 = *(const float4*)(aptr + kc * 64);
    float4 a1 = *(const float4*)(aptr + kc * 64 + 4);
    u16x8 h;
    h[0] = f32_to_bf16(a0.x); h[1] = f32_to_bf16(a0.y);
    h[2] = f32_to_bf16(a0.z); h[3] = f32_to_bf16(a0.w);
    h[4] = f32_to_bf16(a1.x); h[5] = f32_to_bf16(a1.y);
    h[6] = f32_to_bf16(a1.z); h[7] = f32_to_bf16(a1.w);
    *(u16x8*)&As[buf][slot] = h;
  };

  const unsigned short* bbase = WT + (size_t)(n0 + l15) * kH + quad * 8;
  auto load_b = [&](bf16x8 (&dst)[2][4], int kc) {
#pragma unroll
    for (int kh = 0; kh < 2; ++kh)
#pragma unroll
      for (int ni = 0; ni < 4; ++ni)
        dst[kh][ni] =
            *(const bf16x8*)(bbase + (size_t)(ni * 16) * kH + kc * 64 + kh * 32);
  };

  bf16x8 bcur[2][4];
  stage(0, 0);
  load_b(bcur, 0);
  __syncthreads();

#pragma unroll
  for (int kc = 0; kc < 8; ++kc) {
    bf16x8 bnxt[2][4];
    if (kc < 7) {
      load_b(bnxt, kc + 1);            // L2 loads: consumed next iteration
      stage(kc + 1, (kc + 1) & 1);     // HBM/L3 loads: consumed next iteration
    }
    bf16x8 afr[2][4];
#pragma unroll
    for (int kh = 0; kh < 2; ++kh)
#pragma unroll
      for (int mi = 0; mi < 4; ++mi)
        afr[kh][mi] = *(const bf16x8*)&As[kc & 1][((kh * 4 + mi) * 64 + lane) * 8];
#pragma unroll
    for (int kh = 0; kh < 2; ++kh)
#pragma unroll
      for (int mi = 0; mi < 4; ++mi)
#pragma unroll
        for (int ni = 0; ni < 4; ++ni)
          acc[mi][ni] = __builtin_amdgcn_mfma_f32_16x16x32_bf16(
              afr[kh][mi], bcur[kh][ni], acc[mi][ni], 0, 0, 0);
    if (kc < 7) {
#pragma unroll
      for (int kh = 0; kh < 2; ++kh)
#pragma unroll
        for (int ni = 0; ni < 4; ++ni) bcur[kh][ni] = bnxt[kh][ni];
      __syncthreads();
    }
  }

  // fused epilogue; C/D layout: col = n0+16ni+l15, row = 16mi+quad*4+reg
  float dec4[4], vv4[4], wc4[4];
#pragma unroll
  for (int ni = 0; ni < 4; ++ni) {
    const int col = n0 + 16 * ni + l15;
    dec4[ni] = dec_fea[b * kH + col];
    vv4[ni] = v[col];
    if constexpr (IS_NODE) wc4[ni] = W_c[col]; else wc4[ni] = 0.f;
  }
#pragma unroll
  for (int mi = 0; mi < 4; ++mi) {
#pragma unroll
    for (int reg = 0; reg < 4; ++reg) {
      const int row = 16 * mi + quad * 4 + reg;
      float fl = 0.f;
      if constexpr (IS_NODE) fl = flow[b * kNK + row0 + row];
      float p = 0.f;
#pragma unroll
      for (int ni = 0; ni < 4; ++ni) {
        float val = acc[mi][ni][reg] + dec4[ni];
        if constexpr (IS_NODE) val = fmaf(fl, wc4[ni], val);
        p += tanh_fast(val) * vv4[ni];
      }
#pragma unroll
      for (int off = 1; off < 16; off <<= 1) p += __shfl_xor(p, off, 64);
      if (l15 == 0) red[wave][row] = p;
    }
  }
  __syncthreads();
  if (tid < 64) {
    float s = 0.f;
#pragma unroll
    for (int w = 0; w < 8; ++w) s += red[w][tid];
    scores[b * ROWS + row0 + tid] = s;
  }
}

// ---------------------------------------------------------------- softmax/mix
// softmax -> *mask -> renorm  ==  e*m / sum(e*m)  (first denominator cancels).
// Scores are tanh-bounded (|s| <= ||v||_1 ~ 7), so no max subtraction needed.
__device__ __forceinline__ float block_sum_512(float v, float* rbuf) {
#pragma unroll
  for (int off = 32; off >= 1; off >>= 1) v += __shfl_xor(v, off, 64);
  if ((threadIdx.x & 63) == 0) rbuf[threadIdx.x >> 6] = v;
  __syncthreads();
  float s = rbuf[0];
#pragma unroll
  for (int w = 1; w < 8; ++w) s += rbuf[w];
  __syncthreads();
  return s;
}

__global__ __launch_bounds__(512) void softmax_mix_kernel(
    const float* __restrict__ scores_node, const float* __restrict__ scores_tok,
    const int* __restrict__ node_to_token,
    const float* __restrict__ mask_tok, const float* __restrict__ mask_node,
    float* __restrict__ out_final, float* __restrict__ out_attn_node) {
  const int b = blockIdx.x, tid = threadIdx.x;
  __shared__ float an_sh[kNK];
  __shared__ float rbuf[8];

  // node attention
  float en = 0.f;
  if (tid < kNK)
    en = expf(scores_node[b * kNK + tid]) * mask_node[b * kNK + tid];
  float sn = block_sum_512(en, rbuf);
  float an = en / sn;
  if (tid < kNK) {
    an_sh[tid] = an;
    out_attn_node[b * kNK + tid] = an;
  }
  __syncthreads();

  // gather onto tokens + renorm-softmax
  const float mt = mask_tok[b * kTK + tid];
  const int idx = node_to_token[b * kTK + tid];
  float eg = expf(an_sh[idx]) * mt;
  float sg = block_sum_512(eg, rbuf);
  float an2t = eg / sg;

  // token attention
  float et = expf(scores_tok[b * kTK + tid]) * mt;
  float st = block_sum_512(et, rbuf);
  float at = et / st;

  out_final[b * kTK + tid] = 0.5f * (at + an2t);
}

// ---------------------------------------------------------------- c_t (partial + reduce)
// grid (8, 64): block (slice s, batch b); each handles 64 token rows.
__global__ __launch_bounds__(512) void ct_partial_kernel(
    const float* __restrict__ final_attn, const float* __restrict__ enc_tok,
    float* __restrict__ ctp) {
  const int s = blockIdx.x, b = blockIdx.y, h = threadIdx.x;
  __shared__ float fa[64];
  if (h < 64) fa[h] = final_attn[b * kTK + s * 64 + h];
  __syncthreads();
  float acc = 0.f;
  const float* base = enc_tok + ((size_t)(b * kTK + s * 64)) * kH + h;
#pragma unroll 8
  for (int t = 0; t < 64; ++t) acc = fmaf(fa[t], base[(size_t)t * kH], acc);
  ctp[(size_t)(b * 8 + s) * kH + h] = acc;
}

__global__ __launch_bounds__(512) void ct_reduce_kernel(
    const float* __restrict__ ctp, float* __restrict__ out_ct) {
  const int b = blockIdx.x, h = threadIdx.x;
  float acc = 0.f;
#pragma unroll
  for (int s = 0; s < 8; ++s) acc += ctp[(size_t)(b * 8 + s) * kH + h];
  out_ct[b * kH + h] = acc;
}

// ---------------------------------------------------------------- graph 2-hop
__global__ __launch_bounds__(256) void flow1_kernel(
    const float* __restrict__ attn_node, const float* __restrict__ graph,
    float* __restrict__ fp1) {
  const int s = blockIdx.x, b = blockIdx.y, m = threadIdx.x;
  __shared__ float z[32];
  if (m < 32) z[m] = attn_node[b * kNK + s * 32 + m];
  __syncthreads();
  float acc = 0.f;
  const float* g = graph + ((size_t)(b * kNK + s * 32)) * kNK + m;
#pragma unroll 8
  for (int n = 0; n < 32; ++n) acc = fmaf(z[n], g[(size_t)n * kNK], acc);
  fp1[(b * 8 + s) * kNK + m] = acc;
}

__global__ __launch_bounds__(256) void flow3_kernel(
    const float* __restrict__ fp1, const float* __restrict__ graph,
    float* __restrict__ fp2) {
  const int s = blockIdx.x, b = blockIdx.y, m = threadIdx.x;
  __shared__ float one[32];
  if (m < 32) {
    float o = 0.f;
#pragma unroll
    for (int sp = 0; sp < 8; ++sp) o += fp1[(b * 8 + sp) * kNK + s * 32 + m];
    one[m] = o;
  }
  __syncthreads();
  float acc = 0.f;
  const float* g = graph + ((size_t)(b * kNK + s * 32)) * kNK + m;
#pragma unroll 8
  for (int n = 0; n < 32; ++n) acc = fmaf(one[n], g[(size_t)n * kNK], acc);
  fp2[(b * 8 + s) * kNK + m] = acc;
}

__global__ __launch_bounds__(256) void flow4_kernel(
    const float* __restrict__ fp1, const float* __restrict__ fp2,
    const float* __restrict__ attn_node, float* __restrict__ out_flow) {
  const int b = blockIdx.x, m = threadIdx.x;
  float one = 0.f, two = 0.f;
#pragma unroll
  for (int s = 0; s < 8; ++s) {
    one += fp1[(b * 8 + s) * kNK + m];
    two += fp2[(b * 8 + s) * kNK + m];
  }
  out_flow[b * kNK + m] = (attn_node[b * kNK + m] + one + two) * 0.33333f;
}

// ---------------------------------------------------------------- launch
extern "C" void kernel_launch(void* const* d_in, const int* in_sizes, int n_in,
                              void* d_out, int out_size, void* d_ws, size_t ws_size,
                              hipStream_t stream) {
  (void)in_sizes; (void)n_in; (void)out_size; (void)ws_size;
  const float* s_t_hat  = (const float*)d_in[0];
  const float* enc_tok  = (const float*)d_in[1];
  const float* enc_node = (const float*)d_in[2];
  const int*   n2t      = (const int*)d_in[3];
  const float* mask_tok = (const float*)d_in[4];
  const float* mask_nd  = (const float*)d_in[5];
  const float* graph    = (const float*)d_in[6];
  const float* flow     = (const float*)d_in[7];
  const float* W_c      = (const float*)d_in[8];
  const float* W_tok    = (const float*)d_in[9];
  const float* W_node   = (const float*)d_in[10];
  const float* W_dec    = (const float*)d_in[11];
  const float* b_dec    = (const float*)d_in[12];
  const float* v_tok    = (const float*)d_in[13];
  const float* v_node   = (const float*)d_in[14];

  float* out = (float*)d_out;   // c_t | final_attn | attn_dist_node | flow_out
  float* out_ct        = out;
  float* out_final     = out + kB * kH;
  float* out_attn_node = out + 2 * kB * kH;
  float* out_flow      = out_attn_node + kB * kNK;

  // workspace layout (float offsets):
  float* ws = (float*)d_ws;
  float* dec_fea_buf = ws;                   // 32768
  float* scores_tok  = ws + 32768;           // 32768
  float* scores_node = ws + 65536;           // 16384
  float* fp1         = ws + 81920;           // 131072
  float* fp2         = ws + 212992;          // 131072
  float* dec_part    = ws + 344064;          // 262144 (aliased by ctp later)
  float* ctp         = dec_part;             // 64*8*512 = 262144
  unsigned short* WtokT  = (unsigned short*)(ws + 606208);  // 131072 ushorts
  unsigned short* WnodeT = WtokT + kH * kH;                 // 131072 ushorts
  // total: 737280 floats ~ 2.95 MB

  transpose_w_kernel<<<dim3(16, 16, 2), dim3(32, 8), 0, stream>>>(
      W_tok, W_node, WtokT, WnodeT);
  dec_partial_kernel<<<dim3(kB, 8), 512, 0, stream>>>(s_t_hat, W_dec, dec_part);
  dec_reduce_kernel<<<kB, 512, 0, stream>>>(dec_part, b_dec, dec_fea_buf);
  scores_kernel<kTK, false><<<kB * kTK / 64, 512, 0, stream>>>(
      enc_tok, WtokT, dec_fea_buf, nullptr, nullptr, v_tok, scores_tok);
  scores_kernel<kNK, true><<<kB * kNK / 64, 512, 0, stream>>>(
      enc_node, WnodeT, dec_fea_buf, flow, W_c, v_node, scores_node);
  softmax_mix_kernel<<<kB, 512, 0, stream>>>(scores_node, scores_tok, n2t,
                                             mask_tok, mask_nd, out_final, out_attn_node);
  ct_partial_kernel<<<dim3(8, kB), 512, 0, stream>>>(out_final, enc_tok, ctp);
  ct_reduce_kernel<<<kB, 512, 0, stream>>>(ctp, out_ct);
  flow1_kernel<<<dim3(8, kB), 256, 0, stream>>>(out_attn_node, graph, fp1);
  flow3_kernel<<<dim3(8, kB), 256, 0, stream>>>(fp1, graph, fp2);
  flow4_kernel<<<kB, 256, 0, stream>>>(fp1, fp2, out_attn_node, out_flow);
}

// Round 4
// 243.673 us; speedup vs baseline: 1.3896x; 1.0180x over previous
//
#include <hip/hip_runtime.h>
#include <math.h>

// Problem constants (reference: B=64, TK=512, NK=256, H=512, fp32 in/out)
constexpr int kB = 64;
constexpr int kTK = 512;
constexpr int kNK = 256;
constexpr int kH = 512;
constexpr int kTokBlocks = kB * kTK / 64;   // 512
constexpr int kNodeBlocks = kB * kNK / 64;  // 256

typedef float f32x4 __attribute__((ext_vector_type(4)));
typedef __bf16 bf16x8 __attribute__((ext_vector_type(8)));
typedef unsigned short u16x8 __attribute__((ext_vector_type(8)));

__device__ __forceinline__ unsigned short f32_to_bf16(float f) {
  // round-half-up: same 0.5-ulp bound as RNE, 1 op cheaper
  return (unsigned short)((__float_as_uint(f) + 0x8000u) >> 16);
}

__device__ __forceinline__ float tanh_fast(float x) {
  float e = __builtin_amdgcn_exp2f(x * 2.8853900817779268f);  // e^{2x}
  return 1.0f - 2.0f * __builtin_amdgcn_rcpf(e + 1.0f);
}

// CK-style block_sync_lds: drain LDS only, leave global loads (vmcnt) in
// flight across the barrier. imm: vmcnt=63 (0xF | 0xC000), expcnt=7 (0x70),
// lgkmcnt=0 (bits 11:8 = 0) -> 0xC07F.
__device__ __forceinline__ void lds_barrier() {
  __builtin_amdgcn_s_waitcnt(0xC07F);
  __builtin_amdgcn_s_barrier();
}

// ---------------------------------------------------------- prep kernel
// blocks [0,512): W transpose->bf16 [n][k] (2 matrices x 256 tiles)
// blocks [512,1024): dec_fea partials (b, k-slice of 128) -> dec_part[b][8][512]
__global__ __launch_bounds__(256) void prep_kernel(
    const float* __restrict__ Wtok, const float* __restrict__ Wnode,
    unsigned short* __restrict__ WtokT, unsigned short* __restrict__ WnodeT,
    const float* __restrict__ s_t_hat, const float* __restrict__ W_dec,
    float* __restrict__ dec_part) {
  __shared__ float sm[32 * 33];
  const int tid = threadIdx.x;
  if (blockIdx.x < 512) {
    const int idx = blockIdx.x;
    const int z = idx >> 8, rem = idx & 255;
    const int bx = rem & 15, by = rem >> 4;
    const float* W = z ? Wnode : Wtok;
    unsigned short* T = z ? WnodeT : WtokT;
    const int tx = tid & 31, ty = tid >> 5;
#pragma unroll
    for (int i = 0; i < 4; ++i)
      sm[(ty + 8 * i) * 33 + tx] =
          W[(size_t)(by * 32 + ty + 8 * i) * kH + bx * 32 + tx];
    __syncthreads();
#pragma unroll
    for (int i = 0; i < 4; ++i)
      T[(size_t)(bx * 32 + ty + 8 * i) * kH + by * 32 + tx] =
          f32_to_bf16(sm[tx * 33 + ty + 8 * i]);
  } else {
    const int r = blockIdx.x - 512;
    const int b = r >> 3, s = r & 7;
    if (tid < 128) sm[tid] = s_t_hat[(size_t)b * 1024 + s * 128 + tid];
    __syncthreads();
    float a0 = 0.f, a1 = 0.f;
    const float* w = W_dec + (size_t)(s * 128) * kH;
#pragma unroll 8
    for (int k = 0; k < 128; ++k) {
      a0 = fmaf(sm[k], w[(size_t)k * kH + tid], a0);
      a1 = fmaf(sm[k], w[(size_t)k * kH + tid + 256], a1);
    }
    dec_part[(size_t)(b * 8 + s) * kH + tid] = a0;
    dec_part[(size_t)(b * 8 + s) * kH + tid + 256] = a1;
  }
}

// ---------------------------------------------------------- fused scores
// 1024 threads = 16 waves. Block tile 64 rows x 512 cols, BK=128, 4 chunks.
// Wave w owns cols [32w,32w+32): 4(m) x 2(n) tiles of mfma 16x16x32_bf16.
// A: fp32->bf16 staged into LDS frag-major (one 16B slot per thread/chunk),
//    double-buffered; global loads issued one FULL chunk early.
// B: bf16 [n][k] direct from global (L2-hot), one MFMA-group lookahead.
// Sync: lds_barrier() keeps global loads in flight across chunk boundaries.
__global__ __launch_bounds__(1024, 4) void scores_fused_kernel(
    const float* __restrict__ enc_tok, const float* __restrict__ enc_node,
    const unsigned short* __restrict__ WtokT,
    const unsigned short* __restrict__ WnodeT,
    const float* __restrict__ dec_part, const float* __restrict__ b_dec,
    const float* __restrict__ flow, const float* __restrict__ W_c,
    const float* __restrict__ v_tok, const float* __restrict__ v_node,
    float* __restrict__ scores_tok, float* __restrict__ scores_node) {
  const int tid = threadIdx.x;
  const int wave = tid >> 6, lane = tid & 63;
  const int quad = lane >> 4, l15 = lane & 15;
  const bool is_node = blockIdx.x >= kTokBlocks;
  const int bidx = is_node ? (int)blockIdx.x - kTokBlocks : (int)blockIdx.x;
  const float* A = is_node ? enc_node : enc_tok;
  const unsigned short* WT = is_node ? WnodeT : WtokT;
  const float* v = is_node ? v_node : v_tok;
  float* scores = is_node ? scores_node : scores_tok;
  const int ROWS = is_node ? kNK : kTK;
  const int b = is_node ? (bidx >> 2) : (bidx >> 3);
  const int row0 = (is_node ? (bidx & 3) : (bidx & 7)) * 64;

  __shared__ __align__(16) unsigned short As[2][8192];  // 16 KB x2
  __shared__ float red[16][64];

  const f32x4 fzero = {0.f, 0.f, 0.f, 0.f};
  f32x4 acc[4][2];
#pragma unroll
  for (int i = 0; i < 4; ++i)
#pragma unroll
    for (int j = 0; j < 2; ++j) acc[i][j] = fzero;

  // A staging: thread tid owns LDS slot tid (16B). slot -> (row,k):
  //   mi = (slot>>6)&3, l15s = slot&15, kh = slot>>8, quads = (slot>>4)&3
  //   row = mi*16 + l15s ; k = kh*32 + quads*8  (+ j in [0,8))
  const int arow = ((tid >> 6) & 3) * 16 + (tid & 15);
  const int akk = (tid >> 8) * 32 + ((tid >> 4) & 3) * 8;
  const float* aptr = A + (size_t)(b * ROWS + row0 + arow) * kH + akk;
  float4 ax0, ax1;
  auto aload = [&](int kc) {
    ax0 = *(const float4*)(aptr + kc * 128);
    ax1 = *(const float4*)(aptr + kc * 128 + 4);
  };
  auto acommit = [&](int buf) {
    u16x8 h;
    h[0] = f32_to_bf16(ax0.x); h[1] = f32_to_bf16(ax0.y);
    h[2] = f32_to_bf16(ax0.z); h[3] = f32_to_bf16(ax0.w);
    h[4] = f32_to_bf16(ax1.x); h[5] = f32_to_bf16(ax1.y);
    h[6] = f32_to_bf16(ax1.z); h[7] = f32_to_bf16(ax1.w);
    *(u16x8*)&As[buf][tid * 8] = h;
  };

  const int n0 = wave * 32;
  const unsigned short* bbase = WT + (size_t)(n0 + l15) * kH + quad * 8;
  bf16x8 bbuf[2][2];
  auto loadB = [&](int sb, int g) {
    bbuf[sb][0] = *(const bf16x8*)(bbase + g * 32);
    bbuf[sb][1] = *(const bf16x8*)(bbase + (size_t)16 * kH + g * 32);
  };

  aload(0);
  acommit(0);          // chunk0 -> buf0 (waits vmcnt once)
  aload(1);            // chunk1 in flight
  loadB(0, 0);
  lds_barrier();

#pragma unroll
  for (int g = 0; g < 16; ++g) {
    const int kc = g >> 2, kh = g & 3;
    if (kh == 0 && kc < 3) {
      acommit((kc + 1) & 1);   // ax holds chunk kc+1 (issued 4 groups ago)
      if (kc < 2) aload(kc + 2);
    }
    if (g < 15) loadB((g + 1) & 1, g + 1);
    bf16x8 afr[4];
#pragma unroll
    for (int mi = 0; mi < 4; ++mi)
      afr[mi] = *(const bf16x8*)&As[kc & 1][((kh * 4 + mi) * 64 + lane) * 8];
#pragma unroll
    for (int mi = 0; mi < 4; ++mi)
#pragma unroll
      for (int ni = 0; ni < 2; ++ni)
        acc[mi][ni] = __builtin_amdgcn_mfma_f32_16x16x32_bf16(
            afr[mi], bbuf[g & 1][ni], acc[mi][ni], 0, 0, 0);
    if (kh == 3 && kc < 3) lds_barrier();
  }

  // epilogue; C/D: col = n0+16ni+l15, row = 16mi+quad*4+reg
  float dec2[2], vv2[2], wc2[2];
#pragma unroll
  for (int ni = 0; ni < 2; ++ni) {
    const int col = n0 + 16 * ni + l15;
    float d = b_dec[col];
#pragma unroll
    for (int p = 0; p < 8; ++p) d += dec_part[(size_t)(b * 8 + p) * kH + col];
    dec2[ni] = d;
    vv2[ni] = v[col];
    wc2[ni] = is_node ? W_c[col] : 0.f;
  }
#pragma unroll
  for (int mi = 0; mi < 4; ++mi) {
#pragma unroll
    for (int reg = 0; reg < 4; ++reg) {
      const int row = 16 * mi + quad * 4 + reg;
      const float fl = is_node ? flow[b * kNK + row0 + row] : 0.f;
      float p = 0.f;
#pragma unroll
      for (int ni = 0; ni < 2; ++ni)
        p += tanh_fast(fmaf(fl, wc2[ni], acc[mi][ni][reg] + dec2[ni])) * vv2[ni];
#pragma unroll
      for (int off = 1; off < 16; off <<= 1) p += __shfl_xor(p, off, 64);
      if (l15 == 0) red[wave][row] = p;
    }
  }
  __syncthreads();
  if (tid < 64) {
    float s = 0.f;
#pragma unroll
    for (int w = 0; w < 16; ++w) s += red[w][tid];
    scores[b * ROWS + row0 + tid] = s;
  }
}

// ---------------------------------------------------------- softmax/mix (+zero flow)
// softmax -> *mask -> renorm == e*m / sum(e*m); tanh-bounded scores, no max-sub.
__device__ __forceinline__ float block_sum_512(float v, float* rbuf) {
#pragma unroll
  for (int off = 32; off >= 1; off >>= 1) v += __shfl_xor(v, off, 64);
  if ((threadIdx.x & 63) == 0) rbuf[threadIdx.x >> 6] = v;
  __syncthreads();
  float s = rbuf[0];
#pragma unroll
  for (int w = 1; w < 8; ++w) s += rbuf[w];
  __syncthreads();
  return s;
}

__global__ __launch_bounds__(512) void softmax_mix_kernel(
    const float* __restrict__ scores_node, const float* __restrict__ scores_tok,
    const int* __restrict__ node_to_token,
    const float* __restrict__ mask_tok, const float* __restrict__ mask_node,
    float* __restrict__ out_final, float* __restrict__ out_attn_node,
    float* __restrict__ out_flow) {
  const int b = blockIdx.x, tid = threadIdx.x;
  __shared__ float an_sh[kNK];
  __shared__ float rbuf[8];

  if (tid < kNK) out_flow[b * kNK + tid] = 0.f;  // init for round-5 atomics

  float en = 0.f;
  if (tid < kNK)
    en = expf(scores_node[b * kNK + tid]) * mask_node[b * kNK + tid];
  float sn = block_sum_512(en, rbuf);
  float an = en / sn;
  if (tid < kNK) {
    an_sh[tid] = an;
    out_attn_node[b * kNK + tid] = an;
  }
  __syncthreads();

  const float mt = mask_tok[b * kTK + tid];
  const int idx = node_to_token[b * kTK + tid];
  float eg = expf(an_sh[idx]) * mt;
  float sg = block_sum_512(eg, rbuf);
  float an2t = eg / sg;

  float et = expf(scores_tok[b * kTK + tid]) * mt;
  float st = block_sum_512(et, rbuf);
  float at = et / st;

  out_final[b * kTK + tid] = 0.5f * (at + an2t);
}

// ---------------------------------------------------------- ct_partial + flow1
// blocks [0,512): ct partial (s,b) over 64 token rows.
// blocks [512,768): one_hop partials (sl,b): fp1[b][8][256].
__global__ __launch_bounds__(512) void ct_flow1_kernel(
    const float* __restrict__ final_attn, const float* __restrict__ enc_tok,
    const float* __restrict__ attn_node, const float* __restrict__ graph,
    float* __restrict__ ctp, float* __restrict__ fp1) {
  __shared__ float sm[64];
  const int tid = threadIdx.x;
  if (blockIdx.x < 512) {
    const int s = blockIdx.x & 7, b = blockIdx.x >> 3;
    if (tid < 64) sm[tid] = final_attn[b * kTK + s * 64 + tid];
    __syncthreads();
    float acc = 0.f;
    const float* base = enc_tok + ((size_t)(b * kTK + s * 64)) * kH + tid;
#pragma unroll 16
    for (int t = 0; t < 64; ++t) acc = fmaf(sm[t], base[(size_t)t * kH], acc);
    ctp[(size_t)(b * 8 + s) * kH + tid] = acc;
  } else {
    const int r = blockIdx.x - 512;
    const int b = r >> 2, sl = r & 3;
    const int m = tid & 255, half = tid >> 8;
    if (tid < 64) sm[tid] = attn_node[b * kNK + sl * 64 + tid];
    __syncthreads();
    float acc = 0.f;
    const float* g =
        graph + ((size_t)(b * kNK + sl * 64 + half * 32)) * kNK + m;
#pragma unroll 8
    for (int n = 0; n < 32; ++n)
      acc = fmaf(sm[half * 32 + n], g[(size_t)n * kNK], acc);
    fp1[(size_t)(b * 8 + sl * 2 + half) * kNK + m] = acc;
  }
}

// ---------------------------------------------------------- ct_reduce + flow 2-hop
// blocks [0,64): ct reduce. blocks [64,320): (sl,b): reconstruct one_hop slice,
// add (z+one)/3 for own slice + atomic two-hop partials for all m.
__global__ __launch_bounds__(512) void ct_flow2_kernel(
    const float* __restrict__ ctp, const float* __restrict__ fp1,
    const float* __restrict__ attn_node, const float* __restrict__ graph,
    float* __restrict__ out_ct, float* __restrict__ out_flow) {
  __shared__ float one_sh[64];
  const int tid = threadIdx.x;
  if (blockIdx.x < 64) {
    const int b = blockIdx.x;
    float acc = 0.f;
#pragma unroll
    for (int p = 0; p < 8; ++p) acc += ctp[(size_t)(b * 8 + p) * kH + tid];
    out_ct[b * kH + tid] = acc;
  } else {
    const int r = blockIdx.x - 64;
    const int b = r >> 2, sl = r & 3;
    const int m = tid & 255, half = tid >> 8;
    if (tid < 64) {
      const int n = sl * 64 + tid;
      float one = 0.f;
#pragma unroll
      for (int p = 0; p < 8; ++p) one += fp1[(size_t)(b * 8 + p) * kNK + n];
      one_sh[tid] = one;
      atomicAdd(&out_flow[b * kNK + n],
                (attn_node[b * kNK + n] + one) * 0.33333f);
    }
    __syncthreads();
    float acc = 0.f;
    const float* g =
        graph + ((size_t)(b * kNK + sl * 64 + half * 32)) * kNK + m;
#pragma unroll 8
    for (int n = 0; n < 32; ++n)
      acc = fmaf(one_sh[half * 32 + n], g[(size_t)n * kNK], acc);
    atomicAdd(&out_flow[b * kNK + m], acc * 0.33333f);
  }
}

// ---------------------------------------------------------------- launch
extern "C" void kernel_launch(void* const* d_in, const int* in_sizes, int n_in,
                              void* d_out, int out_size, void* d_ws, size_t ws_size,
                              hipStream_t stream) {
  (void)in_sizes; (void)n_in; (void)out_size; (void)ws_size;
  const float* s_t_hat  = (const float*)d_in[0];
  const float* enc_tok  = (const float*)d_in[1];
  const float* enc_node = (const float*)d_in[2];
  const int*   n2t      = (const int*)d_in[3];
  const float* mask_tok = (const float*)d_in[4];
  const float* mask_nd  = (const float*)d_in[5];
  const float* graph    = (const float*)d_in[6];
  const float* flow     = (const float*)d_in[7];
  const float* W_c      = (const float*)d_in[8];
  const float* W_tok    = (const float*)d_in[9];
  const float* W_node   = (const float*)d_in[10];
  const float* W_dec    = (const float*)d_in[11];
  const float* b_dec    = (const float*)d_in[12];
  const float* v_tok    = (const float*)d_in[13];
  const float* v_node   = (const float*)d_in[14];

  float* out = (float*)d_out;   // c_t | final_attn | attn_dist_node | flow_out
  float* out_ct        = out;
  float* out_final     = out + kB * kH;
  float* out_attn_node = out + 2 * kB * kH;
  float* out_flow      = out_attn_node + kB * kNK;

  // workspace (float offsets):
  float* ws = (float*)d_ws;
  float* scores_tok  = ws;                    // 32768
  float* scores_node = ws + 32768;            // 16384
  float* dec_part    = ws + 49152;            // 262144 (consumed by scores)
  float* ctp         = dec_part;              // alias: written after scores done
  float* fp1         = ws + 311296;           // 131072
  unsigned short* WtokT  = (unsigned short*)(ws + 442368);  // 65536 f
  unsigned short* WnodeT = WtokT + kH * kH;                 // 65536 f
  // total 573440 floats = 2.29 MB

  prep_kernel<<<1024, 256, 0, stream>>>(W_tok, W_node, WtokT, WnodeT,
                                        s_t_hat, W_dec, dec_part);
  scores_fused_kernel<<<kTokBlocks + kNodeBlocks, 1024, 0, stream>>>(
      enc_tok, enc_node, WtokT, WnodeT, dec_part, b_dec, flow, W_c,
      v_tok, v_node, scores_tok, scores_node);
  softmax_mix_kernel<<<kB, 512, 0, stream>>>(scores_node, scores_tok, n2t,
                                             mask_tok, mask_nd, out_final,
                                             out_attn_node, out_flow);
  ct_flow1_kernel<<<768, 512, 0, stream>>>(out_final, enc_tok, out_attn_node,
                                           graph, ctp, fp1);
  ct_flow2_kernel<<<320, 512, 0, stream>>>(ctp, fp1, out_attn_node, graph,
                                           out_ct, out_flow);
}

// Round 5
// 241.830 us; speedup vs baseline: 1.4002x; 1.0076x over previous
//
#include <hip/hip_runtime.h>
#include <math.h>

// Problem constants (reference: B=64, TK=512, NK=256, H=512, fp32 in/out)
constexpr int kB = 64;
constexpr int kTK = 512;
constexpr int kNK = 256;
constexpr int kH = 512;
constexpr int kTokBlocks = kB * kTK / 64;   // 512
constexpr int kNodeBlocks = kB * kNK / 64;  // 256

typedef float f32x4 __attribute__((ext_vector_type(4)));
typedef __bf16 bf16x8 __attribute__((ext_vector_type(8)));

__device__ __forceinline__ unsigned short f32_to_bf16(float f) {
  return (unsigned short)((__float_as_uint(f) + 0x8000u) >> 16);
}

__device__ __forceinline__ float tanh_fast(float x) {
  float e = __builtin_amdgcn_exp2f(x * 2.8853900817779268f);  // e^{2x}
  return 1.0f - 2.0f * __builtin_amdgcn_rcpf(e + 1.0f);
}

// CK-style: drain LDS only, leave global loads in flight across the barrier.
__device__ __forceinline__ void lds_barrier() {
  __builtin_amdgcn_s_waitcnt(0xC07F);
  __builtin_amdgcn_s_barrier();
}

// ---------------------------------------------------------- prep kernel
// blocks [0,512): W transpose->bf16 [n][k]; blocks [512,1024): dec partials.
__global__ __launch_bounds__(256) void prep_kernel(
    const float* __restrict__ Wtok, const float* __restrict__ Wnode,
    unsigned short* __restrict__ WtokT, unsigned short* __restrict__ WnodeT,
    const float* __restrict__ s_t_hat, const float* __restrict__ W_dec,
    float* __restrict__ dec_part) {
  __shared__ float sm[32 * 33];
  const int tid = threadIdx.x;
  if (blockIdx.x < 512) {
    const int idx = blockIdx.x;
    const int z = idx >> 8, rem = idx & 255;
    const int bx = rem & 15, by = rem >> 4;
    const float* W = z ? Wnode : Wtok;
    unsigned short* T = z ? WnodeT : WtokT;
    const int tx = tid & 31, ty = tid >> 5;
#pragma unroll
    for (int i = 0; i < 4; ++i)
      sm[(ty + 8 * i) * 33 + tx] =
          W[(size_t)(by * 32 + ty + 8 * i) * kH + bx * 32 + tx];
    __syncthreads();
#pragma unroll
    for (int i = 0; i < 4; ++i)
      T[(size_t)(bx * 32 + ty + 8 * i) * kH + by * 32 + tx] =
          f32_to_bf16(sm[tx * 33 + ty + 8 * i]);
  } else {
    const int r = blockIdx.x - 512;
    const int b = r >> 3, s = r & 7;
    if (tid < 128) sm[tid] = s_t_hat[(size_t)b * 1024 + s * 128 + tid];
    __syncthreads();
    float a0 = 0.f, a1 = 0.f;
    const float* w = W_dec + (size_t)(s * 128) * kH;
#pragma unroll 8
    for (int k = 0; k < 128; ++k) {
      a0 = fmaf(sm[k], w[(size_t)k * kH + tid], a0);
      a1 = fmaf(sm[k], w[(size_t)k * kH + tid + 256], a1);
    }
    dec_part[(size_t)(b * 8 + s) * kH + tid] = a0;
    dec_part[(size_t)(b * 8 + s) * kH + tid + 256] = a1;
  }
}

// ---------------------------------------------------------- fused scores
// 1024 threads = 16 waves. Block tile 64 rows x 512 cols, BK=128, 4 chunks.
// Wave w owns cols [32w,32w+32): 4(m) x 2(n) tiles of mfma 16x16x32_bf16.
// A staging is DENSE: thread (r = tid>>4, kcol = tid&15) loads float4 at
// row r, k = kc*128 + {0,64} + kcol*4 -> each 16-lane group reads a 256 B
// contiguous run (4 runs/instr at 2 KB stride). LDS commit lands in the
// frag-major slots the MFMA readers expect (reads unchanged from round 4).
__global__ __launch_bounds__(1024, 4) void scores_fused_kernel(
    const float* __restrict__ enc_tok, const float* __restrict__ enc_node,
    const unsigned short* __restrict__ WtokT,
    const unsigned short* __restrict__ WnodeT,
    const float* __restrict__ dec_part, const float* __restrict__ b_dec,
    const float* __restrict__ flow, const float* __restrict__ W_c,
    const float* __restrict__ v_tok, const float* __restrict__ v_node,
    float* __restrict__ scores_tok, float* __restrict__ scores_node) {
  const int tid = threadIdx.x;
  const int wave = tid >> 6, lane = tid & 63;
  const int quad = lane >> 4, l15 = lane & 15;
  const bool is_node = blockIdx.x >= kTokBlocks;
  const int bidx = is_node ? (int)blockIdx.x - kTokBlocks : (int)blockIdx.x;
  const float* A = is_node ? enc_node : enc_tok;
  const unsigned short* WT = is_node ? WnodeT : WtokT;
  const float* v = is_node ? v_node : v_tok;
  float* scores = is_node ? scores_node : scores_tok;
  const int ROWS = is_node ? kNK : kTK;
  const int b = is_node ? (bidx >> 2) : (bidx >> 3);
  const int row0 = (is_node ? (bidx & 3) : (bidx & 7)) * 64;

  __shared__ __align__(16) unsigned short As[2][8192];  // 16 KB x2
  __shared__ float red[16][64];

  const f32x4 fzero = {0.f, 0.f, 0.f, 0.f};
  f32x4 acc[4][2];
#pragma unroll
  for (int i = 0; i < 4; ++i)
#pragma unroll
    for (int j = 0; j < 2; ++j) acc[i][j] = fzero;

  // dense A staging map
  const int r = tid >> 4;      // 0..63 (row)
  const int kcol = tid & 15;   // k-segment
  const float* aptr = A + (size_t)(b * ROWS + row0 + r) * kH + kcol * 4;
  // LDS ushort addr for element (r,k): slot*8 + (k&7),
  // slot = ((k>>5)*4 + (r>>4))*64 + ((k>>3)&3)*16 + (r&15)
  const int k0 = kcol * 4;
  const int k1 = 64 + kcol * 4;
  const int addr0 = (((k0 >> 5) * 4 + (r >> 4)) * 64 + ((k0 >> 3) & 3) * 16 +
                     (r & 15)) * 8 + (k0 & 7);
  const int addr1 = (((k1 >> 5) * 4 + (r >> 4)) * 64 + ((k1 >> 3) & 3) * 16 +
                     (r & 15)) * 8 + (k1 & 7);
  float4 ax0, ax1;
  auto aload = [&](int kc) {
    ax0 = *(const float4*)(aptr + kc * 128);
    ax1 = *(const float4*)(aptr + kc * 128 + 64);
  };
  auto acommit = [&](int buf) {
    ushort4 h0, h1;
    h0.x = f32_to_bf16(ax0.x); h0.y = f32_to_bf16(ax0.y);
    h0.z = f32_to_bf16(ax0.z); h0.w = f32_to_bf16(ax0.w);
    h1.x = f32_to_bf16(ax1.x); h1.y = f32_to_bf16(ax1.y);
    h1.z = f32_to_bf16(ax1.z); h1.w = f32_to_bf16(ax1.w);
    *(ushort4*)&As[buf][addr0] = h0;
    *(ushort4*)&As[buf][addr1] = h1;
  };

  const int n0 = wave * 32;
  const unsigned short* bbase = WT + (size_t)(n0 + l15) * kH + quad * 8;
  bf16x8 bbuf[2][2];
  auto loadB = [&](int sb, int g) {
    bbuf[sb][0] = *(const bf16x8*)(bbase + g * 32);
    bbuf[sb][1] = *(const bf16x8*)(bbase + (size_t)16 * kH + g * 32);
  };

  aload(0);
  acommit(0);
  aload(1);
  loadB(0, 0);
  lds_barrier();

#pragma unroll
  for (int g = 0; g < 16; ++g) {
    const int kc = g >> 2, kh = g & 3;
    if (kh == 0 && kc < 3) {
      acommit((kc + 1) & 1);   // ax holds chunk kc+1 (issued 4 groups ago)
      if (kc < 2) aload(kc + 2);
    }
    if (g < 15) loadB((g + 1) & 1, g + 1);
    bf16x8 afr[4];
#pragma unroll
    for (int mi = 0; mi < 4; ++mi)
      afr[mi] = *(const bf16x8*)&As[kc & 1][((kh * 4 + mi) * 64 + lane) * 8];
#pragma unroll
    for (int mi = 0; mi < 4; ++mi)
#pragma unroll
      for (int ni = 0; ni < 2; ++ni)
        acc[mi][ni] = __builtin_amdgcn_mfma_f32_16x16x32_bf16(
            afr[mi], bbuf[g & 1][ni], acc[mi][ni], 0, 0, 0);
    if (kh == 3 && kc < 3) lds_barrier();
  }

  // epilogue; C/D: col = n0+16ni+l15, row = 16mi+quad*4+reg
  float dec2[2], vv2[2], wc2[2];
#pragma unroll
  for (int ni = 0; ni < 2; ++ni) {
    const int col = n0 + 16 * ni + l15;
    float d = b_dec[col];
#pragma unroll
    for (int p = 0; p < 8; ++p) d += dec_part[(size_t)(b * 8 + p) * kH + col];
    dec2[ni] = d;
    vv2[ni] = v[col];
    wc2[ni] = is_node ? W_c[col] : 0.f;
  }
#pragma unroll
  for (int mi = 0; mi < 4; ++mi) {
#pragma unroll
    for (int reg = 0; reg < 4; ++reg) {
      const int row = 16 * mi + quad * 4 + reg;
      const float fl = is_node ? flow[b * kNK + row0 + row] : 0.f;
      float p = 0.f;
#pragma unroll
      for (int ni = 0; ni < 2; ++ni)
        p += tanh_fast(fmaf(fl, wc2[ni], acc[mi][ni][reg] + dec2[ni])) * vv2[ni];
#pragma unroll
      for (int off = 1; off < 16; off <<= 1) p += __shfl_xor(p, off, 64);
      if (l15 == 0) red[wave][row] = p;
    }
  }
  __syncthreads();
  if (tid < 64) {
    float s = 0.f;
#pragma unroll
    for (int w = 0; w < 16; ++w) s += red[w][tid];
    scores[b * ROWS + row0 + tid] = s;
  }
}

// ---------------------------------------------------------- softmax/mix (+zero flow)
__device__ __forceinline__ float block_sum_512(float v, float* rbuf) {
#pragma unroll
  for (int off = 32; off >= 1; off >>= 1) v += __shfl_xor(v, off, 64);
  if ((threadIdx.x & 63) == 0) rbuf[threadIdx.x >> 6] = v;
  __syncthreads();
  float s = rbuf[0];
#pragma unroll
  for (int w = 1; w < 8; ++w) s += rbuf[w];
  __syncthreads();
  return s;
}

__global__ __launch_bounds__(512) void softmax_mix_kernel(
    const float* __restrict__ scores_node, const float* __restrict__ scores_tok,
    const int* __restrict__ node_to_token,
    const float* __restrict__ mask_tok, const float* __restrict__ mask_node,
    float* __restrict__ out_final, float* __restrict__ out_attn_node,
    float* __restrict__ out_flow) {
  const int b = blockIdx.x, tid = threadIdx.x;
  __shared__ float an_sh[kNK];
  __shared__ float rbuf[8];

  if (tid < kNK) out_flow[b * kNK + tid] = 0.f;  // init for flow2 atomics

  float en = 0.f;
  if (tid < kNK)
    en = expf(scores_node[b * kNK + tid]) * mask_node[b * kNK + tid];
  float sn = block_sum_512(en, rbuf);
  float an = en / sn;
  if (tid < kNK) {
    an_sh[tid] = an;
    out_attn_node[b * kNK + tid] = an;
  }
  __syncthreads();

  const float mt = mask_tok[b * kTK + tid];
  const int idx = node_to_token[b * kTK + tid];
  float eg = expf(an_sh[idx]) * mt;
  float sg = block_sum_512(eg, rbuf);
  float an2t = eg / sg;

  float et = expf(scores_tok[b * kTK + tid]) * mt;
  float st = block_sum_512(et, rbuf);
  float at = et / st;

  out_final[b * kTK + tid] = 0.5f * (at + an2t);
}

// ---------------------------------------------------------- ct_partial + flow1
// blocks [0,128): ct partial (b, s-half of 256 rows); thread owns a float4
//   h-group and 64 rows -> 1 KB contiguous per wave-instr.
// blocks [128,384): one_hop partials (b, sl of 64 n-rows), float4 over m,
//   in-block reduce over nsub -> fp1[b][4][256].
__global__ __launch_bounds__(512) void ct_flow1_kernel(
    const float* __restrict__ final_attn, const float* __restrict__ enc_tok,
    const float* __restrict__ attn_node, const float* __restrict__ graph,
    float* __restrict__ ctp, float* __restrict__ fp1) {
  const int tid = threadIdx.x;
  if (blockIdx.x < 128) {
    const int b = blockIdx.x >> 1, s = blockIdx.x & 1;
    __shared__ float fa[256];
    if (tid < 256) fa[tid] = final_attn[b * kTK + s * 256 + tid];
    __syncthreads();
    const int h4 = (tid & 127) * 4, tsub = tid >> 7;
    float4 acc = {0.f, 0.f, 0.f, 0.f};
    const float* base =
        enc_tok + ((size_t)(b * kTK + s * 256 + tsub * 64)) * kH + h4;
#pragma unroll 8
    for (int t = 0; t < 64; ++t) {
      float4 e = *(const float4*)(base + (size_t)t * kH);
      const float w = fa[tsub * 64 + t];
      acc.x = fmaf(w, e.x, acc.x); acc.y = fmaf(w, e.y, acc.y);
      acc.z = fmaf(w, e.z, acc.z); acc.w = fmaf(w, e.w, acc.w);
    }
    *(float4*)&ctp[((size_t)(b * 8 + s * 4 + tsub)) * kH + h4] = acc;
  } else {
    const int rr = blockIdx.x - 128;
    const int b = rr >> 2, sl = rr & 3;
    __shared__ float z[64];
    __shared__ float part[8][256];
    if (tid < 64) z[tid] = attn_node[b * kNK + sl * 64 + tid];
    __syncthreads();
    const int m4 = (tid & 63) * 4, nsub = tid >> 6;
    float4 acc = {0.f, 0.f, 0.f, 0.f};
    const float* g =
        graph + ((size_t)(b * kNK + sl * 64 + nsub * 8)) * kNK + m4;
#pragma unroll
    for (int n = 0; n < 8; ++n) {
      float4 gg = *(const float4*)(g + (size_t)n * kNK);
      const float w = z[nsub * 8 + n];
      acc.x = fmaf(w, gg.x, acc.x); acc.y = fmaf(w, gg.y, acc.y);
      acc.z = fmaf(w, gg.z, acc.z); acc.w = fmaf(w, gg.w, acc.w);
    }
    *(float4*)&part[nsub][m4] = acc;
    __syncthreads();
    if (tid < 64) {
      float4 s0 = {0.f, 0.f, 0.f, 0.f};
#pragma unroll
      for (int p = 0; p < 8; ++p) {
        float4 pp = *(const float4*)&part[p][tid * 4];
        s0.x += pp.x; s0.y += pp.y; s0.z += pp.z; s0.w += pp.w;
      }
      *(float4*)&fp1[((size_t)(b * 4 + sl)) * kNK + tid * 4] = s0;
    }
  }
}

// ---------------------------------------------------------- ct_reduce + flow 2-hop
__global__ __launch_bounds__(512) void ct_flow2_kernel(
    const float* __restrict__ ctp, const float* __restrict__ fp1,
    const float* __restrict__ attn_node, const float* __restrict__ graph,
    float* __restrict__ out_ct, float* __restrict__ out_flow) {
  const int tid = threadIdx.x;
  if (blockIdx.x < 64) {
    const int b = blockIdx.x;
    __shared__ float acc_sh[4][512];
    const int h4 = (tid & 127) * 4, part = tid >> 7;
    float4 a = {0.f, 0.f, 0.f, 0.f};
#pragma unroll
    for (int j = 0; j < 2; ++j) {
      float4 c = *(const float4*)&ctp[((size_t)(b * 8 + part * 2 + j)) * kH + h4];
      a.x += c.x; a.y += c.y; a.z += c.z; a.w += c.w;
    }
    *(float4*)&acc_sh[part][h4] = a;
    __syncthreads();
    if (tid < 128) {
      float4 s = {0.f, 0.f, 0.f, 0.f};
#pragma unroll
      for (int p = 0; p < 4; ++p) {
        float4 pp = *(const float4*)&acc_sh[p][tid * 4];
        s.x += pp.x; s.y += pp.y; s.z += pp.z; s.w += pp.w;
      }
      *(float4*)&out_ct[b * kH + tid * 4] = s;
    }
  } else {
    const int rr = blockIdx.x - 64;
    const int b = rr >> 2, sl = rr & 3;
    __shared__ float one_sh[64];
    __shared__ float part2[8][256];
    if (tid < 64) {
      const int n = sl * 64 + tid;
      float one = 0.f;
#pragma unroll
      for (int p = 0; p < 4; ++p) one += fp1[((size_t)(b * 4 + p)) * kNK + n];
      one_sh[tid] = one;
      atomicAdd(&out_flow[b * kNK + n],
                (attn_node[b * kNK + n] + one) * 0.33333f);
    }
    __syncthreads();
    const int m4 = (tid & 63) * 4, nsub = tid >> 6;
    float4 acc = {0.f, 0.f, 0.f, 0.f};
    const float* g =
        graph + ((size_t)(b * kNK + sl * 64 + nsub * 8)) * kNK + m4;
#pragma unroll
    for (int n = 0; n < 8; ++n) {
      float4 gg = *(const float4*)(g + (size_t)n * kNK);
      const float w = one_sh[sl * 0 + nsub * 8 + n];
      acc.x = fmaf(w, gg.x, acc.x); acc.y = fmaf(w, gg.y, acc.y);
      acc.z = fmaf(w, gg.z, acc.z); acc.w = fmaf(w, gg.w, acc.w);
    }
    *(float4*)&part2[nsub][m4] = acc;
    __syncthreads();
    if (tid < 64) {
      float4 s = {0.f, 0.f, 0.f, 0.f};
#pragma unroll
      for (int p = 0; p < 8; ++p) {
        float4 pp = *(const float4*)&part2[p][tid * 4];
        s.x += pp.x; s.y += pp.y; s.z += pp.z; s.w += pp.w;
      }
      float* dst = &out_flow[b * kNK + tid * 4];
      atomicAdd(dst + 0, s.x * 0.33333f);
      atomicAdd(dst + 1, s.y * 0.33333f);
      atomicAdd(dst + 2, s.z * 0.33333f);
      atomicAdd(dst + 3, s.w * 0.33333f);
    }
  }
}

// ---------------------------------------------------------------- launch
extern "C" void kernel_launch(void* const* d_in, const int* in_sizes, int n_in,
                              void* d_out, int out_size, void* d_ws, size_t ws_size,
                              hipStream_t stream) {
  (void)in_sizes; (void)n_in; (void)out_size; (void)ws_size;
  const float* s_t_hat  = (const float*)d_in[0];
  const float* enc_tok  = (const float*)d_in[1];
  const float* enc_node = (const float*)d_in[2];
  const int*   n2t      = (const int*)d_in[3];
  const float* mask_tok = (const float*)d_in[4];
  const float* mask_nd  = (const float*)d_in[5];
  const float* graph    = (const float*)d_in[6];
  const float* flow     = (const float*)d_in[7];
  const float* W_c      = (const float*)d_in[8];
  const float* W_tok    = (const float*)d_in[9];
  const float* W_node   = (const float*)d_in[10];
  const float* W_dec    = (const float*)d_in[11];
  const float* b_dec    = (const float*)d_in[12];
  const float* v_tok    = (const float*)d_in[13];
  const float* v_node   = (const float*)d_in[14];

  float* out = (float*)d_out;   // c_t | final_attn | attn_dist_node | flow_out
  float* out_ct        = out;
  float* out_final     = out + kB * kH;
  float* out_attn_node = out + 2 * kB * kH;
  float* out_flow      = out_attn_node + kB * kNK;

  // workspace (float offsets), total ~2.03 MB (<= proven 2.3 MB usage):
  float* ws = (float*)d_ws;
  float* scores_tok  = ws;                    // 32768
  float* scores_node = ws + 32768;            // 16384
  float* dec_part    = ws + 49152;            // 262144 (consumed by scores)
  float* ctp         = dec_part;              // alias: 64*8*512 = 262144
  float* fp1         = ws + 311296;           // 64*4*256 = 65536
  unsigned short* WtokT  = (unsigned short*)(ws + 376832);  // 65536 f
  unsigned short* WnodeT = WtokT + kH * kH;                 // 65536 f

  prep_kernel<<<1024, 256, 0, stream>>>(W_tok, W_node, WtokT, WnodeT,
                                        s_t_hat, W_dec, dec_part);
  scores_fused_kernel<<<kTokBlocks + kNodeBlocks, 1024, 0, stream>>>(
      enc_tok, enc_node, WtokT, WnodeT, dec_part, b_dec, flow, W_c,
      v_tok, v_node, scores_tok, scores_node);
  softmax_mix_kernel<<<kB, 512, 0, stream>>>(scores_node, scores_tok, n2t,
                                             mask_tok, mask_nd, out_final,
                                             out_attn_node, out_flow);
  ct_flow1_kernel<<<384, 512, 0, stream>>>(out_final, enc_tok, out_attn_node,
                                           graph, ctp, fp1);
  ct_flow2_kernel<<<320, 512, 0, stream>>>(ctp, fp1, out_attn_node, graph,
                                           out_ct, out_flow);
}